// Round 1
// baseline (563.986 us; speedup 1.0000x reference)
//
#include <hip/hip_runtime.h>
#include <hip/hip_bf16.h>
#include <math.h>

// Problem constants (reference: B=8, N=2048, F=128, W=64)
constexpr int B = 8;
constexpr int N = 2048;
constexpr int F = 128;
constexpr int W = 64;

constexpr int TQ = 64;   // query tile rows per block
constexpr int TK = 64;   // key tile cols per iteration

// ---------------------------------------------------------------------------
// Projection kernel: one block per (b,n) row; 256 threads = 256 output cols
// cols [0,64): queries, [64,128): keys, [128,256): values
// ---------------------------------------------------------------------------
__global__ __launch_bounds__(256) void proj_kernel(
    const float* __restrict__ x,
    const float* __restrict__ wq,
    const float* __restrict__ wk,
    const float* __restrict__ wv,
    float* __restrict__ q,
    float* __restrict__ k,
    float* __restrict__ v) {
  const int row = blockIdx.x;          // 0 .. B*N-1
  const int tid = threadIdx.x;

  __shared__ float xs[F];
  if (tid < F) xs[tid] = x[row * F + tid];
  __syncthreads();

  const float* w;
  float* outp;
  int wcols, c;
  if (tid < 64) {
    w = wq; wcols = W; c = tid;        outp = q + row * W + c;
  } else if (tid < 128) {
    w = wk; wcols = W; c = tid - 64;   outp = k + row * W + c;
  } else {
    w = wv; wcols = F; c = tid - 128;  outp = v + row * F + c;
  }

  float acc = 0.f;
#pragma unroll 8
  for (int f = 0; f < F; ++f) acc += xs[f] * w[f * wcols + c];
  *outp = acc;
}

// ---------------------------------------------------------------------------
// Flash-attention kernel (fp32, online softmax).
// Grid: (N/TQ, B). Block: 256 threads as a 16x16 grid.
//   thread(ty,tx): S rows i0..i0+3 (i0=ty*4), S cols jx..jx+3 (jx=tx*4)
//                  O rows i0..i0+3, O cols f0..f0+7 (f0=tx*8)
// ---------------------------------------------------------------------------
__global__ __launch_bounds__(256) void attn_kernel(
    const float* __restrict__ q,
    const float* __restrict__ k,
    const float* __restrict__ v,
    float* __restrict__ out) {
  __shared__ __align__(16) float qs[W][TQ];   // Q^T tile  (16 KB)
  __shared__ __align__(16) float ks[W][TK];   // K^T tile  (16 KB)
  __shared__ __align__(16) float vs[TK][F];   // V tile    (32 KB)
  __shared__ __align__(16) float ps[TK][TQ];  // P^T tile  (16 KB)

  const int b  = blockIdx.y;
  const int qt = blockIdx.x;
  const int tid = threadIdx.x;
  const int ty = tid >> 4;        // 0..15
  const int tx = tid & 15;        // 0..15
  const int i0 = ty * 4;          // row offset in tile
  const int jx = tx * 4;          // S col offset
  const int f0 = tx * 8;          // O col offset

  const float* qb = q + (size_t)(b * N + qt * TQ) * W;
  const float* kb = k + (size_t)b * N * W;
  const float* vb = v + (size_t)b * N * F;

  // Load Q tile transposed: qs[w][i] = Q[i][w]
  for (int e = tid; e < TQ * W; e += 256) {
    int i = e / W, w = e % W;
    qs[w][i] = qb[e];
  }

  float m_r[4], l_r[4];
  float o_acc[4][8];
#pragma unroll
  for (int r = 0; r < 4; ++r) {
    m_r[r] = -INFINITY;
    l_r[r] = 0.f;
#pragma unroll
    for (int c = 0; c < 8; ++c) o_acc[r][c] = 0.f;
  }

  for (int kt = 0; kt < N / TK; ++kt) {
    __syncthreads();  // previous PV done (and qs ready on first iter)

    // Load K tile transposed: ks[w][j] = K[kt*TK + j][w]
    const float* kp = kb + (size_t)kt * TK * W;
    for (int e = tid; e < TK * W; e += 256) {
      int j = e / W, w = e % W;
      ks[w][j] = kp[e];
    }
    // Load V tile (row-major, contiguous) with float4
    const float* vp = vb + (size_t)kt * TK * F;
    float4* vdst = (float4*)&vs[0][0];
    const float4* vsrc = (const float4*)vp;
    for (int e = tid; e < TK * F / 4; e += 256) vdst[e] = vsrc[e];

    __syncthreads();

    // S = Q K^T  (4x4 micro-tile per thread)
    float s[4][4];
#pragma unroll
    for (int r = 0; r < 4; ++r)
#pragma unroll
      for (int c = 0; c < 4; ++c) s[r][c] = 0.f;

    for (int w = 0; w < W; ++w) {
      float4 qv = *(const float4*)&qs[w][i0];
      float4 kv = *(const float4*)&ks[w][jx];
      float qa[4] = {qv.x, qv.y, qv.z, qv.w};
      float ka[4] = {kv.x, kv.y, kv.z, kv.w};
#pragma unroll
      for (int r = 0; r < 4; ++r)
#pragma unroll
        for (int c = 0; c < 4; ++c) s[r][c] += qa[r] * ka[c];
    }

    // Online softmax per row; 16 lanes (same ty) share each row.
#pragma unroll
    for (int r = 0; r < 4; ++r) {
      float mx = fmaxf(fmaxf(s[r][0], s[r][1]), fmaxf(s[r][2], s[r][3]));
#pragma unroll
      for (int off = 1; off < 16; off <<= 1)
        mx = fmaxf(mx, __shfl_xor(mx, off, 64));

      float mnew = fmaxf(m_r[r], mx);
      float alpha = __expf(m_r[r] - mnew);  // 0 on first tile (m=-inf)

      float p[4];
      float psum = 0.f;
#pragma unroll
      for (int c = 0; c < 4; ++c) {
        p[c] = __expf(s[r][c] - mnew);
        psum += p[c];
      }
#pragma unroll
      for (int off = 1; off < 16; off <<= 1)
        psum += __shfl_xor(psum, off, 64);

      l_r[r] = l_r[r] * alpha + psum;
      m_r[r] = mnew;

      // Write P transposed: ps[j][i] = P[i][j]
#pragma unroll
      for (int c = 0; c < 4; ++c) ps[jx + c][i0 + r] = p[c];

      // Rescale existing O rows
#pragma unroll
      for (int c = 0; c < 8; ++c) o_acc[r][c] *= alpha;
    }

    __syncthreads();  // P visible to all

    // O += P V  (4 rows x 8 cols per thread)
    for (int j = 0; j < TK; ++j) {
      float4 pv = *(const float4*)&ps[j][i0];
      float pr[4] = {pv.x, pv.y, pv.z, pv.w};
      float4 v0 = *(const float4*)&vs[j][f0];
      float4 v1 = *(const float4*)&vs[j][f0 + 4];
      float vv[8] = {v0.x, v0.y, v0.z, v0.w, v1.x, v1.y, v1.z, v1.w};
#pragma unroll
      for (int r = 0; r < 4; ++r)
#pragma unroll
        for (int c = 0; c < 8; ++c) o_acc[r][c] += pr[r] * vv[c];
    }
  }

  // Epilogue: normalize and store
  float* ob = out + (size_t)(b * N + qt * TQ) * F;
#pragma unroll
  for (int r = 0; r < 4; ++r) {
    float inv = 1.f / l_r[r];
    float4 s0 = make_float4(o_acc[r][0] * inv, o_acc[r][1] * inv,
                            o_acc[r][2] * inv, o_acc[r][3] * inv);
    float4 s1 = make_float4(o_acc[r][4] * inv, o_acc[r][5] * inv,
                            o_acc[r][6] * inv, o_acc[r][7] * inv);
    *(float4*)&ob[(i0 + r) * F + f0] = s0;
    *(float4*)&ob[(i0 + r) * F + f0 + 4] = s1;
  }
}

// ---------------------------------------------------------------------------
// Launch
// ---------------------------------------------------------------------------
extern "C" void kernel_launch(void* const* d_in, const int* in_sizes, int n_in,
                              void* d_out, int out_size, void* d_ws, size_t ws_size,
                              hipStream_t stream) {
  // setup_inputs order: x, adj(unused), w_key, w_value, w_query
  const float* x  = (const float*)d_in[0];
  const float* wk = (const float*)d_in[2];
  const float* wv = (const float*)d_in[3];
  const float* wq = (const float*)d_in[4];
  float* out = (float*)d_out;

  // Workspace layout: Q | K | V  (fp32)
  float* q_ws = (float*)d_ws;                  // B*N*W
  float* k_ws = q_ws + (size_t)B * N * W;      // B*N*W
  float* v_ws = k_ws + (size_t)B * N * W;      // B*N*F
  // total = 8*2048*(64+64+128)*4 = 16 MB

  proj_kernel<<<B * N, 256, 0, stream>>>(x, wq, wk, wv, q_ws, k_ws, v_ws);

  dim3 grid(N / TQ, B);
  attn_kernel<<<grid, 256, 0, stream>>>(q_ws, k_ws, v_ws, out);
}

// Round 3
// 301.441 us; speedup vs baseline: 1.8710x; 1.8710x over previous
//
#include <hip/hip_runtime.h>
#include <hip/hip_bf16.h>
#include <math.h>

// Problem constants: B=8, N=2048, F=128, W=64
constexpr int B = 8;
constexpr int N = 2048;
constexpr int F = 128;
constexpr int W = 64;

constexpr int TQ = 64;   // query rows per attention block
constexpr int TK = 64;   // key rows per K-tile iteration

typedef short bf16x8 __attribute__((ext_vector_type(8)));   // 8 bf16 in 4 VGPRs
typedef float f32x4  __attribute__((ext_vector_type(4)));   // MFMA accumulator

__device__ inline ushort f2bf(float f) {
  union { float f; uint u; } v; v.f = f;
  uint u = v.u;
  return (ushort)((u + 0x7FFFu + ((u >> 16) & 1u)) >> 16);  // RNE
}
__device__ inline float bf2f(ushort h) {
  union { uint u; float f; } v; v.u = ((uint)h) << 16;
  return v.f;
}
__device__ inline void splitbf(float f, ushort& hi, ushort& lo) {
  ushort h = f2bf(f);
  hi = h;
  lo = f2bf(f - bf2f(h));
}

// ---------------------------------------------------------------------------
// prep_w: build concatenated transposed weight wt_{hi,lo}[256][128] bf16.
// wt[n][k] = W*[k][n] with n in [0,64)=Q, [64,128)=K, [128,256)=V.
// ---------------------------------------------------------------------------
__global__ __launch_bounds__(256) void prep_w(
    const float* __restrict__ wq, const float* __restrict__ wk,
    const float* __restrict__ wv, ushort* __restrict__ wth,
    ushort* __restrict__ wtl) {
  int gid = blockIdx.x * 256 + threadIdx.x;   // 4096 threads total
  int n = gid >> 4;                            // 0..255 feature
  int k0 = (gid & 15) * 8;
  ushort th[8], tl[8];
#pragma unroll
  for (int j = 0; j < 8; ++j) {
    int k = k0 + j;
    float val = (n < 64)  ? wq[k * W + n]
              : (n < 128) ? wk[k * W + (n - 64)]
                          : wv[k * F + (n - 128)];
    splitbf(val, th[j], tl[j]);
  }
  *(uint4*)&wth[n * 128 + k0] = *(uint4*)th;
  *(uint4*)&wtl[n * 128 + k0] = *(uint4*)tl;
}

// ---------------------------------------------------------------------------
// proj: [Q|K|V] = x @ Wcat via split-bf16 MFMA. Block = 64 x-rows, 4 waves.
// Q,K stored as split (hi,lo) row-major; V stored transposed vt[b][f][n].
// ---------------------------------------------------------------------------
constexpr int KP = 136;  // 128 + 8 pad

__global__ __launch_bounds__(256) void proj_kernel(
    const float* __restrict__ x,
    const ushort* __restrict__ wth, const ushort* __restrict__ wtl,
    ushort* __restrict__ q_h, ushort* __restrict__ q_l,
    ushort* __restrict__ k_h, ushort* __restrict__ k_l,
    ushort* __restrict__ vt_ws) {
  __shared__ ushort xsh[64][KP];    // x hi
  __shared__ ushort xsl[64][KP];    // x lo
  __shared__ ushort wsh[128][KP];   // w hi (half of wt at a time)
  __shared__ ushort wsl[128][KP];   // w lo

  const int tid  = threadIdx.x;
  const int wid  = tid >> 6;
  const int lane = tid & 63;
  const int g = lane >> 4, li = lane & 15;
  const int brow0 = blockIdx.x * 64;
  const int b    = brow0 / N;
  const int nloc = brow0 % N;

  // stage x tile (fp32 -> split bf16)
  for (int idx = tid; idx < 64 * 128 / 4; idx += 256) {
    int row = idx >> 5, c4 = idx & 31;
    float4 xv = *(const float4*)&x[(size_t)(brow0 + row) * F + c4 * 4];
    ushort4 h, l;
    splitbf(xv.x, h.x, l.x); splitbf(xv.y, h.y, l.y);
    splitbf(xv.z, h.z, l.z); splitbf(xv.w, h.w, l.w);
    *(ushort4*)&xsh[row][c4 * 4] = h;
    *(ushort4*)&xsl[row][c4 * 4] = l;
  }
  // stage wt rows 0..127 (Q|K features)
  for (int idx = tid; idx < 128 * 128 / 8; idx += 256) {
    int row = idx >> 4, c8 = idx & 15;
    *(uint4*)&wsh[row][c8 * 8] = *(const uint4*)&wth[row * 128 + c8 * 8];
    *(uint4*)&wsl[row][c8 * 8] = *(const uint4*)&wtl[row * 128 + c8 * 8];
  }
  __syncthreads();

  // A-fragments from this wave's 16 x-rows (reused for both passes)
  bf16x8 xah[4], xal[4];
#pragma unroll
  for (int kk = 0; kk < 4; ++kk) {
    xah[kk] = *(const bf16x8*)&xsh[wid * 16 + li][kk * 32 + g * 8];
    xal[kk] = *(const bf16x8*)&xsl[wid * 16 + li][kk * 32 + g * 8];
  }

  f32x4 zero = {0.f, 0.f, 0.f, 0.f};

  // ---- pass 1: QK features, D[row][feat] ----
  f32x4 accqk[8];
#pragma unroll
  for (int t = 0; t < 8; ++t) accqk[t] = zero;
#pragma unroll
  for (int kk = 0; kk < 4; ++kk)
#pragma unroll
    for (int nt = 0; nt < 8; ++nt) {
      bf16x8 bh = *(const bf16x8*)&wsh[nt * 16 + li][kk * 32 + g * 8];
      bf16x8 bl = *(const bf16x8*)&wsl[nt * 16 + li][kk * 32 + g * 8];
      accqk[nt] = __builtin_amdgcn_mfma_f32_16x16x32_bf16(xah[kk], bh, accqk[nt], 0, 0, 0);
      accqk[nt] = __builtin_amdgcn_mfma_f32_16x16x32_bf16(xah[kk], bl, accqk[nt], 0, 0, 0);
      accqk[nt] = __builtin_amdgcn_mfma_f32_16x16x32_bf16(xal[kk], bh, accqk[nt], 0, 0, 0);
    }
#pragma unroll
  for (int nt = 0; nt < 8; ++nt)
#pragma unroll
    for (int r = 0; r < 4; ++r) {
      int row = brow0 + wid * 16 + g * 4 + r;
      int c = nt * 16 + li;
      ushort hv, lv;
      splitbf(accqk[nt][r], hv, lv);
      if (c < 64) { q_h[row * W + c] = hv;        q_l[row * W + c] = lv; }
      else        { k_h[row * W + (c - 64)] = hv; k_l[row * W + (c - 64)] = lv; }
    }

  // ---- pass 2: V features, swapped operands -> D[feat][row] (coalesced vt) ----
  __syncthreads();
  for (int idx = tid; idx < 128 * 128 / 8; idx += 256) {
    int row = idx >> 4, c8 = idx & 15;
    *(uint4*)&wsh[row][c8 * 8] = *(const uint4*)&wth[(128 + row) * 128 + c8 * 8];
    *(uint4*)&wsl[row][c8 * 8] = *(const uint4*)&wtl[(128 + row) * 128 + c8 * 8];
  }
  __syncthreads();

  f32x4 accv[8];
#pragma unroll
  for (int t = 0; t < 8; ++t) accv[t] = zero;
#pragma unroll
  for (int kk = 0; kk < 4; ++kk)
#pragma unroll
    for (int mt = 0; mt < 8; ++mt) {
      bf16x8 ah = *(const bf16x8*)&wsh[mt * 16 + li][kk * 32 + g * 8];
      bf16x8 al = *(const bf16x8*)&wsl[mt * 16 + li][kk * 32 + g * 8];
      accv[mt] = __builtin_amdgcn_mfma_f32_16x16x32_bf16(ah, xah[kk], accv[mt], 0, 0, 0);
      accv[mt] = __builtin_amdgcn_mfma_f32_16x16x32_bf16(ah, xal[kk], accv[mt], 0, 0, 0);
      accv[mt] = __builtin_amdgcn_mfma_f32_16x16x32_bf16(al, xah[kk], accv[mt], 0, 0, 0);
    }
#pragma unroll
  for (int mt = 0; mt < 8; ++mt)
#pragma unroll
    for (int r = 0; r < 4; ++r) {
      int f = mt * 16 + g * 4 + r;
      int n = nloc + wid * 16 + li;
      vt_ws[(size_t)b * F * N + (size_t)f * N + n] = f2bf(accv[mt][r]);
    }
}

// ---------------------------------------------------------------------------
// attn: flash attention, split-bf16 S path, fp32 online softmax.
// Grid (N/64, B), 4 waves; wave w owns Q rows w*16..w*16+15.
// ---------------------------------------------------------------------------
constexpr int LP = 72;   // 64 + 8 pad

__global__ __launch_bounds__(256) void attn_kernel(
    const ushort* __restrict__ q_h, const ushort* __restrict__ q_l,
    const ushort* __restrict__ k_h, const ushort* __restrict__ k_l,
    const ushort* __restrict__ vt_ws, float* __restrict__ out) {
  __shared__ ushort qsh[64][LP];
  __shared__ ushort qsl[64][LP];
  __shared__ ushort ksh[64][LP];
  __shared__ ushort ksl[64][LP];
  __shared__ ushort vst[128][LP];     // V^T tile [f][key]
  __shared__ ushort ps[4][16][LP];    // per-wave P scratch

  const int tid  = threadIdx.x;
  const int wid  = tid >> 6;
  const int lane = tid & 63;
  const int g = lane >> 4, li = lane & 15;
  const int b = blockIdx.y, qt = blockIdx.x;

  const size_t qoff = (size_t)(b * N + qt * TQ) * W;
  const ushort* vb = vt_ws + (size_t)b * F * N;

  // load Q tiles (hi+lo)
  for (int idx = tid; idx < 512; idx += 256) {
    int row = idx >> 3, c8 = idx & 7;
    *(uint4*)&qsh[row][c8 * 8] = *(const uint4*)&q_h[qoff + row * W + c8 * 8];
    *(uint4*)&qsl[row][c8 * 8] = *(const uint4*)&q_l[qoff + row * W + c8 * 8];
  }

  float m_r[4], l_r[4];
  f32x4 zero = {0.f, 0.f, 0.f, 0.f};
  f32x4 o_acc[8];
#pragma unroll
  for (int r = 0; r < 4; ++r) { m_r[r] = -INFINITY; l_r[r] = 0.f; }
#pragma unroll
  for (int t = 0; t < 8; ++t) o_acc[t] = zero;

  for (int kt = 0; kt < N / TK; ++kt) {
    __syncthreads();
    const size_t koff = (size_t)b * N * W + (size_t)kt * TK * W;
    for (int idx = tid; idx < 512; idx += 256) {
      int row = idx >> 3, c8 = idx & 7;
      *(uint4*)&ksh[row][c8 * 8] = *(const uint4*)&k_h[koff + row * W + c8 * 8];
      *(uint4*)&ksl[row][c8 * 8] = *(const uint4*)&k_l[koff + row * W + c8 * 8];
    }
    for (int idx = tid; idx < 1024; idx += 256) {
      int f = idx >> 3, c8 = idx & 7;
      *(uint4*)&vst[f][c8 * 8] = *(const uint4*)&vb[(size_t)f * N + kt * TK + c8 * 8];
    }
    __syncthreads();

    // ---- S = Q K^T (split: qh*kh + qh*kl + ql*kh) ----
    bf16x8 qah[2], qal[2];
    qah[0] = *(const bf16x8*)&qsh[wid * 16 + li][g * 8];
    qah[1] = *(const bf16x8*)&qsh[wid * 16 + li][32 + g * 8];
    qal[0] = *(const bf16x8*)&qsl[wid * 16 + li][g * 8];
    qal[1] = *(const bf16x8*)&qsl[wid * 16 + li][32 + g * 8];
    f32x4 s_acc[4];
#pragma unroll
    for (int nt = 0; nt < 4; ++nt) s_acc[nt] = zero;
#pragma unroll
    for (int kk = 0; kk < 2; ++kk)
#pragma unroll
      for (int nt = 0; nt < 4; ++nt) {
        bf16x8 kh = *(const bf16x8*)&ksh[nt * 16 + li][kk * 32 + g * 8];
        bf16x8 kl = *(const bf16x8*)&ksl[nt * 16 + li][kk * 32 + g * 8];
        s_acc[nt] = __builtin_amdgcn_mfma_f32_16x16x32_bf16(qah[kk], kh, s_acc[nt], 0, 0, 0);
        s_acc[nt] = __builtin_amdgcn_mfma_f32_16x16x32_bf16(qah[kk], kl, s_acc[nt], 0, 0, 0);
        s_acc[nt] = __builtin_amdgcn_mfma_f32_16x16x32_bf16(qal[kk], kh, s_acc[nt], 0, 0, 0);
      }

    // ---- online softmax (row = g*4 + r; 16 lanes of same g share a row) ----
    float alpha[4];
#pragma unroll
    for (int r = 0; r < 4; ++r) {
      float mx = fmaxf(fmaxf(s_acc[0][r], s_acc[1][r]),
                       fmaxf(s_acc[2][r], s_acc[3][r]));
#pragma unroll
      for (int off = 1; off < 16; off <<= 1)
        mx = fmaxf(mx, __shfl_xor(mx, off, 64));
      float mnew = fmaxf(m_r[r], mx);
      float a_ = __expf(m_r[r] - mnew);   // 0 on first tile
      float psum = 0.f;
#pragma unroll
      for (int nt = 0; nt < 4; ++nt) {
        float p = __expf(s_acc[nt][r] - mnew);
        ushort ph = f2bf(p);
        psum += bf2f(ph);    // denominator consistent with bf16 numerator
        ps[wid][g * 4 + r][nt * 16 + li] = ph;
      }
#pragma unroll
      for (int off = 1; off < 16; off <<= 1)
        psum += __shfl_xor(psum, off, 64);
      l_r[r] = l_r[r] * a_ + psum;
      m_r[r] = mnew;
      alpha[r] = a_;
    }
#pragma unroll
    for (int t = 0; t < 8; ++t)
#pragma unroll
      for (int r = 0; r < 4; ++r) o_acc[t][r] *= alpha[r];

    // ---- O += P V (P from wave-private LDS scratch; same-wave RAW) ----
#pragma unroll
    for (int kk = 0; kk < 2; ++kk) {
      bf16x8 pa = *(const bf16x8*)&ps[wid][li][kk * 32 + g * 8];
#pragma unroll
      for (int ft = 0; ft < 8; ++ft) {
        bf16x8 vf = *(const bf16x8*)&vst[ft * 16 + li][kk * 32 + g * 8];
        o_acc[ft] = __builtin_amdgcn_mfma_f32_16x16x32_bf16(pa, vf, o_acc[ft], 0, 0, 0);
      }
    }
  }

  // ---- epilogue: normalize, store fp32 ----
  float* ob = out + (size_t)(b * N + qt * TQ) * F;
#pragma unroll
  for (int r = 0; r < 4; ++r) {
    float inv = 1.f / l_r[r];
    int row = wid * 16 + g * 4 + r;
#pragma unroll
    for (int ft = 0; ft < 8; ++ft)
      ob[row * F + ft * 16 + li] = o_acc[ft][r] * inv;
  }
}

// ---------------------------------------------------------------------------
// Launch
// ---------------------------------------------------------------------------
extern "C" void kernel_launch(void* const* d_in, const int* in_sizes, int n_in,
                              void* d_out, int out_size, void* d_ws, size_t ws_size,
                              hipStream_t stream) {
  // setup_inputs order: x, adj(unused), w_key, w_value, w_query
  const float* x  = (const float*)d_in[0];
  const float* wk = (const float*)d_in[2];
  const float* wv = (const float*)d_in[3];
  const float* wq = (const float*)d_in[4];
  float* out = (float*)d_out;

  constexpr size_t BNW = (size_t)B * N * W;   // 1,048,576
  ushort* q_h  = (ushort*)d_ws;
  ushort* q_l  = q_h + BNW;
  ushort* k_h  = q_l + BNW;
  ushort* k_l  = k_h + BNW;
  ushort* vt   = k_l + BNW;                   // B*F*N = 2,097,152
  ushort* wth  = vt + (size_t)B * F * N;      // 32768
  ushort* wtl  = wth + 32768;                 // 32768
  // total ~12.2 MB

  prep_w<<<16, 256, 0, stream>>>(wq, wk, wv, wth, wtl);
  proj_kernel<<<(B * N) / 64, 256, 0, stream>>>(x, wth, wtl,
                                                q_h, q_l, k_h, k_l, vt);
  dim3 grid(N / TQ, B);
  attn_kernel<<<grid, 256, 0, stream>>>(q_h, q_l, k_h, k_l, vt, out);
}